// Round 8
// baseline (164.128 us; speedup 1.0000x reference)
//
#include <hip/hip_runtime.h>

// CircleLoss on MI355X: mean(log1p(exp(-64*(sim*(2*pos-1) - 0.35*64))))
// over the 8192x8192 cosine-sim Gram matrix.
//
// R7 design (from R6 counters: 1500cyc/block-step vs ~200 of pipe work ->
// barrier-amortization + load-issue-distance problem, not vmcnt count):
//   k1: row-norm -> bf16 (unchanged)
//   k2: upper-tri 256x256 Gram tiles, 8 waves (2Mx4N), BK=64, LDS 128KB
//       double-buffer, ONE vmcnt(0)+s_barrier per K-step, stage issued at
//       top of step (full-step cover, T14), setprio MFMA clusters (T5),
//       fused softplus epilogue + one fp32 atomicAdd per block
//   (reduce kernel removed; d_out zeroed via hipMemsetAsync)
//
// ws: [e: N*D u16 bf16 (8.4 MB)]

typedef unsigned short u16;
typedef unsigned int u32;
typedef __attribute__((ext_vector_type(4))) float f32x4;
typedef __attribute__((ext_vector_type(8))) short bf16x8;
typedef __attribute__((ext_vector_type(8))) u16 u16x8;

#define AS1 __attribute__((address_space(1)))
#define AS3 __attribute__((address_space(3)))

// One wave per row (D = 512 = 64 lanes * 8). 1/max(||x||,eps), bf16 RNE out.
__global__ __launch_bounds__(256) void norm_bf16_k(
    const float* __restrict__ emb, u16* __restrict__ e, int N, int D) {
  const int wid = threadIdx.x >> 6, lane = threadIdx.x & 63;
  const int row = blockIdx.x * 4 + wid;
  if (row >= N) return;
  const float* p = emb + (size_t)row * D + lane * 8;
  f32x4 a = *(const f32x4*)p;
  f32x4 b = *(const f32x4*)(p + 4);
  float ss = 0.f;
#pragma unroll
  for (int i = 0; i < 4; ++i) ss += a[i] * a[i] + b[i] * b[i];
#pragma unroll
  for (int o = 32; o >= 1; o >>= 1) ss += __shfl_xor(ss, o, 64);
  const float inv = 1.0f / fmaxf(sqrtf(ss), 1e-8f);
  u16x8 hv;
#pragma unroll
  for (int i = 0; i < 8; ++i) {
    float x = (i < 4 ? a[i] : b[i - 4]) * inv;
    u32 u = __float_as_uint(x);
    u += 0x7FFFu + ((u >> 16) & 1u);  // RNE to bf16
    hv[i] = (u16)(u >> 16);
  }
  *(u16x8*)(e + (size_t)row * D + lane * 8) = hv;
}

// 256x256 upper-tri tile (I<=J), 512 threads = 8 waves in 2(M)x4(N) grid.
// Wave (wr,wc) owns C rows [wr*128,+128) x cols [wc*64,+64) = 8x4 frags of
// mfma_f32_16x16x32_bf16, acc = 8x4 f32x4 (128 VGPR).
//
// LDS per buffer: A = 16 m-frags x 2 ks, B = 16 n-frags x 2 ks; frag = 1KB,
// fragment-ready lane-linear (lane l holds 16B at l*16, from global row
// (l&15), k-octet (l>>4)) -> gload_lds lane-linear write == ds_read_b128
// fragment read; identical gather on A and B so within-octet permutation
// cancels in A.B^T. Conflict-free (measured 0 in R3/R5/R6).
//
// Per K-step: [vmcnt(0); s_barrier]  <- my 8 loads for buf retired + publish
//             stage 8 loads for buf^1 (k+64)   <- full step of cover
//             2 ks x { read b[4]; 2 x { read a[4]; 16 MFMA } }
// Single barrier per step is race-free: buf^1 was last READ during step
// t-1, and every wave's reads landed in registers before it reached this
// barrier; step-t writes (buf^1) and reads (buf) are disjoint.
__global__ __launch_bounds__(512, 2) void gram_loss_k(
    const u16* __restrict__ e, const int* __restrict__ labels,
    float* __restrict__ out, int N, int D, int NT, int nwg, float invNN) {
  // [buf][A=0/B=1][frag(x*2+ks)*512 + lane*8] ; 2*2*16*2*512 u16 = 128 KB
  __shared__ __attribute__((aligned(16))) u16 sL[2][2][32 * 512];
  __shared__ float swred[8];

  const int tid = threadIdx.x, wid = tid >> 6, lane = tid & 63;

  // T1: bijective XCD swizzle (nwg=528=8*66, r8=0 -> x*66+p), contiguous
  // tile chunk per XCD for A-panel L2 reuse.
  const int q8 = nwg >> 3, r8 = nwg & 7;
  const int x = blockIdx.x & 7, p = blockIdx.x >> 3;
  const int bid = (x < r8 ? x * (q8 + 1) : r8 * (q8 + 1) + (x - r8) * q8) + p;

  // tile-index -> upper-triangular (I, J), I <= J
  int I = 0, rem = bid, rl = NT;
  while (rem >= rl) { rem -= rl; ++I; --rl; }
  const int J = I + rem;
  const int i0 = I * 256, j0 = J * 256;

  // Staging: waves 0-3 stage A (frags 0..31), waves 4-7 stage B.
  const int ab = wid >> 2;                 // 0 = A, 1 = B
  const int rbase = ab ? j0 : i0;
  const int f0 = (wid & 3) * 8;            // first frag index for this wave
  u32 goff[8];
#pragma unroll
  for (int q = 0; q < 8; ++q) {
    const int f = f0 + q, mf = f >> 1, ks = f & 1;
    goff[q] = (u32)(rbase + mf * 16 + (lane & 15)) * (u32)D + ks * 32 +
              ((lane >> 4) * 8);
  }

  const f32x4 z = {0.f, 0.f, 0.f, 0.f};
  f32x4 acc[8][4];
#pragma unroll
  for (int m = 0; m < 8; ++m)
#pragma unroll
    for (int n = 0; n < 4; ++n) acc[m][n] = z;

  const int wr = wid >> 2, wc = wid & 3;   // compute-grid role

  auto stage = [&](int buf, int kk) {
#pragma unroll
    for (int q = 0; q < 8; ++q)
      __builtin_amdgcn_global_load_lds((const AS1 void*)(e + goff[q] + kk),
                                       (AS3 void*)(&sL[buf][ab][(f0 + q) * 512]),
                                       16, 0, 0);
  };

  stage(0, 0);  // prologue: 8 loads in flight

#pragma unroll
  for (int t = 0; t < 8; ++t) {
    const int buf = t & 1;
    asm volatile("s_waitcnt vmcnt(0)" ::: "memory");  // my 8 loads for buf done
    __builtin_amdgcn_s_barrier();                     // publish buf / fence reads
    if (t < 7) stage(buf ^ 1, (t + 1) * 64);          // issue early: full-step cover
#pragma unroll
    for (int ks = 0; ks < 2; ++ks) {
      bf16x8 b[4];
#pragma unroll
      for (int n = 0; n < 4; ++n)
        b[n] = *(const bf16x8*)&sL[buf][1][(((wc * 4 + n) << 1) + ks) * 512 + lane * 8];
#pragma unroll
      for (int mh = 0; mh < 2; ++mh) {
        bf16x8 a[4];
#pragma unroll
        for (int m = 0; m < 4; ++m)
          a[m] = *(const bf16x8*)&sL[buf][0]
                     [(((wr * 8 + mh * 4 + m) << 1) + ks) * 512 + lane * 8];
        __builtin_amdgcn_s_setprio(1);
#pragma unroll
        for (int m = 0; m < 4; ++m)
#pragma unroll
          for (int n = 0; n < 4; ++n)
            acc[mh * 4 + m][n] = __builtin_amdgcn_mfma_f32_16x16x32_bf16(
                a[m], b[n], acc[mh * 4 + m][n], 0, 0, 0);
        __builtin_amdgcn_s_setprio(0);
      }
    }
  }

  // Loss epilogue. C/D map (m89-verified): col = lane&15, row = (lane>>4)*4+reg.
  const float C0 = 64.0f * 0.35f;
  float lsum = 0.f;
  const int rb = i0 + wr * 128, cb = j0 + wc * 64;
#pragma unroll
  for (int m = 0; m < 8; ++m) {
    const int gi0 = rb + m * 16 + (lane >> 4) * 4;
#pragma unroll
    for (int n = 0; n < 4; ++n) {
      const int gj = cb + n * 16 + (lane & 15);
      const int lj = labels[gj];
#pragma unroll
      for (int r = 0; r < 4; ++r) {
        const int li = labels[gi0 + r];
        float s = acc[m][n][r];
        float sg = (li == lj) ? s : -s;
        float xv = fmaf(-64.0f, sg, C0);  // -SCALE*(signed - MARGIN)
        float ax = fabsf(xv);
        lsum += fmaxf(xv, 0.f) + __logf(1.0f + __expf(-ax));
      }
    }
  }

#pragma unroll
  for (int o = 32; o >= 1; o >>= 1) lsum += __shfl_xor(lsum, o, 64);
  if (lane == 0) swred[wid] = lsum;
  __syncthreads();
  if (tid == 0) {
    float t = 0.f;
#pragma unroll
    for (int w = 0; w < 8; ++w) t += swred[w];
    const float wgt = (I == J) ? 1.0f : 2.0f;  // off-diag counts twice
    atomicAdd(out, t * wgt * invNN);
  }
}

extern "C" void kernel_launch(void* const* d_in, const int* in_sizes, int n_in,
                              void* d_out, int out_size, void* d_ws, size_t ws_size,
                              hipStream_t stream) {
  const float* emb = (const float*)d_in[0];
  const int* labels = (const int*)d_in[1];
  float* out = (float*)d_out;

  const int N = in_sizes[1];             // 8192
  const int D = in_sizes[0] / N;         // 512
  const int NT = N / 256;                // 32
  const int nTiles = NT * (NT + 1) / 2;  // 528

  u16* e = (u16*)d_ws;

  hipMemsetAsync(out, 0, sizeof(float), stream);  // d_out is 0xAA-poisoned
  norm_bf16_k<<<N / 4, 256, 0, stream>>>(emb, e, N, D);
  gram_loss_k<<<nTiles, 512, 0, stream>>>(e, labels, out, N, D, NT, nTiles,
                                          (float)(1.0 / ((double)N * (double)N)));
}

// Round 13
// 161.132 us; speedup vs baseline: 1.0186x; 1.0186x over previous
//
#include <hip/hip_runtime.h>

// CircleLoss on MI355X: mean(log1p(exp(-64*(sim*(2*pos-1) - 0.35*64))))
// over the 8192x8192 cosine-sim Gram matrix.
//
// R9: m201-style 8-phase counted-vmcnt schedule on the 256x256 geometry.
//   k1: row-norm -> bf16
//   k2: upper-tri 256x256 tiles, 8 waves (2Mx4N), BK=64, 2 K-tiles/iter,
//       8 phases/iter {ds_read; stage half-tile; [vmcnt(4) @ph4/8]; barrier;
//       lgkmcnt(0); 16 MFMA; barrier}, labels in LDS, fused loss epilogue,
//       one fp32 atomicAdd per block.
// ws: [e: N*D u16 bf16 (8.4 MB)]

typedef unsigned short u16;
typedef unsigned int u32;
typedef __attribute__((ext_vector_type(4))) float f32x4;
typedef __attribute__((ext_vector_type(8))) short bf16x8;
typedef __attribute__((ext_vector_type(8))) u16 u16x8;

#define AS1 __attribute__((address_space(1)))
#define AS3 __attribute__((address_space(3)))

__global__ __launch_bounds__(256) void norm_bf16_k(
    const float* __restrict__ emb, u16* __restrict__ e, int N, int D) {
  const int wid = threadIdx.x >> 6, lane = threadIdx.x & 63;
  const int row = blockIdx.x * 4 + wid;
  if (row >= N) return;
  const float* p = emb + (size_t)row * D + lane * 8;
  f32x4 a = *(const f32x4*)p;
  f32x4 b = *(const f32x4*)(p + 4);
  float ss = 0.f;
#pragma unroll
  for (int i = 0; i < 4; ++i) ss += a[i] * a[i] + b[i] * b[i];
#pragma unroll
  for (int o = 32; o >= 1; o >>= 1) ss += __shfl_xor(ss, o, 64);
  const float inv = 1.0f / fmaxf(sqrtf(ss), 1e-8f);
  u16x8 hv;
#pragma unroll
  for (int i = 0; i < 8; ++i) {
    float x = (i < 4 ? a[i] : b[i - 4]) * inv;
    u32 u = __float_as_uint(x);
    u += 0x7FFFu + ((u >> 16) & 1u);
    hv[i] = (u16)(u >> 16);
  }
  *(u16x8*)(e + (size_t)row * D + lane * 8) = hv;
}

// Fragment-linear LDS (1KB/frag, lane l holds 16B at l*16 = global row l&15,
// k-octet l>>4). gload_lds lane-linear write == ds_read_b128 fragment read;
// identical gather on A and B so within-octet k-permutation cancels in AB^T.
// Conflict-free (0 measured, R3-R8). Frag index = mf*2+ks (ks = 32-k half).
//
// Stage schedule per iter i (u=2i buf0, v=2i+1 buf1, w=2i+2, x=2i+3):
//   ph1:A(v)h0 ph2:A(v)h1 ph3:B(w)h0 ph4:B(w)h1+vmcnt(4)
//   ph5:A(w)h0 ph6:A(w)h1 ph7:B(x)h0 ph8:B(x)h1+vmcnt(4)
// Region-free proof: B(u) read only ph1 (RD_B) -> free ph3+; A(u) quads read
// ph1-4 -> free ph5+; B(v) read ph5 -> free ph7+; A(v) read ph5-8 -> freed at
// next iter ph1. vmcnt(4) at ph4 guards v (A(v) last issue ph2; 4 newer),
// at ph8 guards w (A(w) last issue ph6; 4 newer). Never drains fresh loads.
__global__ __launch_bounds__(512, 2) void gram_loss_k(
    const u16* __restrict__ e, const int* __restrict__ labels,
    float* __restrict__ out, int N, int D, int NT, int nwg, float invNN) {
  __shared__ __attribute__((aligned(16))) u16 sL[2][2][32 * 512];  // 128 KB
  __shared__ int sLab[512];
  __shared__ float swred[8];

  const int tid = threadIdx.x, wid = tid >> 6, lane = tid & 63;

  // T1 bijective XCD swizzle (nwg = 528 = 8*66)
  const int q8 = nwg >> 3, r8 = nwg & 7;
  const int xx = blockIdx.x & 7, pp = blockIdx.x >> 3;
  const int bid = (xx < r8 ? xx * (q8 + 1) : r8 * (q8 + 1) + (xx - r8) * q8) + pp;

  int I = 0, rem = bid, rl = NT;
  while (rem >= rl) { rem -= rl; ++I; --rl; }
  const int J = I + rem;
  const int i0 = I * 256, j0 = J * 256;

  if (tid < 256) sLab[tid] = labels[i0 + tid];
  else           sLab[tid] = labels[j0 + tid - 256];

  const int wr = wid >> 2, wc = wid & 3;

  const f32x4 z = {0.f, 0.f, 0.f, 0.f};
  f32x4 acc[8][4];
#pragma unroll
  for (int m = 0; m < 8; ++m)
#pragma unroll
    for (int n = 0; n < 4; ++n) acc[m][n] = z;

  bf16x8 b[4][2];  // B frags of current tile, live across its 4 quadrant phases

// Stage one half-tile: wave w stages frags {H*16+wid, H*16+wid+8} of OP.
#define STG(BUF, OP, TILE, H)                                                 \
  {                                                                           \
    _Pragma("unroll") for (int j = 0; j < 2; ++j) {                           \
      const int frag = (H) * 16 + wid + 8 * j;                                \
      const u32 off = (u32)(((OP) ? j0 : i0) + (frag >> 1) * 16 + (lane & 15)) \
                          * (u32)D +                                          \
                      (TILE) * 64 + (frag & 1) * 32 + ((lane >> 4) * 8);      \
      __builtin_amdgcn_global_load_lds((const AS1 void*)(e + off),            \
                                       (AS3 void*)(&sL[BUF][OP][frag * 512]), \
                                       16, 0, 0);                             \
    }                                                                         \
  }

#define RD_B(BUF)                                                             \
  _Pragma("unroll") for (int n = 0; n < 4; ++n)                               \
  _Pragma("unroll") for (int ks = 0; ks < 2; ++ks)                            \
      b[n][ks] = *(const bf16x8*)&sL[BUF][1]                                  \
                     [(((wc * 4 + n) << 1) + ks) * 512 + lane * 8];

#define VMCNT4 asm volatile("s_waitcnt vmcnt(4)" ::: "memory");
#define VMCNT0 asm volatile("s_waitcnt vmcnt(0)" ::: "memory");

#define PH(BUF, QP, STGS, WAITS)                                              \
  {                                                                           \
    bf16x8 a[2][2];                                                           \
    _Pragma("unroll") for (int mm = 0; mm < 2; ++mm)                          \
    _Pragma("unroll") for (int ks = 0; ks < 2; ++ks)                          \
        a[mm][ks] = *(const bf16x8*)&sL[BUF][0]                               \
            [(((wr * 8 + (QP) * 2 + mm) << 1) + ks) * 512 + lane * 8];        \
    STGS;                                                                     \
    WAITS;                                                                    \
    __builtin_amdgcn_s_barrier();                                             \
    asm volatile("s_waitcnt lgkmcnt(0)" ::: "memory");                        \
    __builtin_amdgcn_sched_barrier(0);                                        \
    __builtin_amdgcn_s_setprio(1);                                            \
    _Pragma("unroll") for (int mm = 0; mm < 2; ++mm)                          \
    _Pragma("unroll") for (int n = 0; n < 4; ++n)                             \
    _Pragma("unroll") for (int ks = 0; ks < 2; ++ks)                          \
        acc[(QP) * 2 + mm][n] = __builtin_amdgcn_mfma_f32_16x16x32_bf16(      \
            a[mm][ks], b[n][ks], acc[(QP) * 2 + mm][n], 0, 0, 0);             \
    __builtin_amdgcn_s_setprio(0);                                            \
    __builtin_amdgcn_s_barrier();                                             \
  }

#define ITER_STD(V, W, X)                                                     \
  RD_B(0) PH(0, 0, STG(1, 0, V, 0), ;)                                        \
  PH(0, 1, STG(1, 0, V, 1), ;)                                                \
  PH(0, 2, STG(0, 1, W, 0), ;)                                                \
  PH(0, 3, STG(0, 1, W, 1), VMCNT4)                                           \
  RD_B(1) PH(1, 0, STG(0, 0, W, 0), ;)                                        \
  PH(1, 1, STG(0, 0, W, 1), ;)                                                \
  PH(1, 2, STG(1, 1, X, 0), ;)                                                \
  PH(1, 3, STG(1, 1, X, 1), VMCNT4)

  // Prologue: tile0 (A,B) + tile1 (B); A(1) comes in iter0 ph1-2.
  STG(0, 0, 0, 0) STG(0, 0, 0, 1) STG(0, 1, 0, 0) STG(0, 1, 0, 1)
  STG(1, 1, 1, 0) STG(1, 1, 1, 1)
  VMCNT4  // tile0 fully retired (t1.B's 4 loads newer, may fly)
  __builtin_amdgcn_s_barrier();

  ITER_STD(1, 2, 3)
  ITER_STD(3, 4, 5)
  ITER_STD(5, 6, 7)
  // iter 3: v=7; w,x don't exist.
  RD_B(0) PH(0, 0, STG(1, 0, 7, 0), ;)
  PH(0, 1, STG(1, 0, 7, 1), ;)
  PH(0, 2, ;, ;)
  PH(0, 3, ;, VMCNT0)
  RD_B(1) PH(1, 0, ;, ;)
  PH(1, 1, ;, ;)
  PH(1, 2, ;, ;)
  PH(1, 3, ;, ;)

#undef ITER_STD
#undef PH
#undef RD_B
#undef STG

  // Loss epilogue. C/D map (m89-verified): col = lane&15, row = (lane>>4)*4+reg.
  const float C0 = 64.0f * 0.35f;
  float lsum = 0.f;
#pragma unroll
  for (int m = 0; m < 8; ++m) {
    const int ri0 = wr * 128 + m * 16 + (lane >> 4) * 4;  // row within tile
#pragma unroll
    for (int n = 0; n < 4; ++n) {
      const int cj = wc * 64 + n * 16 + (lane & 15);      // col within tile
      const int lj = sLab[256 + cj];
#pragma unroll
      for (int r = 0; r < 4; ++r) {
        const int li = sLab[ri0 + r];
        float s = acc[m][n][r];
        float sg = (li == lj) ? s : -s;
        float xv = fmaf(-64.0f, sg, C0);  // -SCALE*(signed - MARGIN)
        float ax = fabsf(xv);
        lsum += fmaxf(xv, 0.f) + __logf(1.0f + __expf(-ax));
      }
    }
  }

#pragma unroll
  for (int o = 32; o >= 1; o >>= 1) lsum += __shfl_xor(lsum, o, 64);
  if (lane == 0) swred[wid] = lsum;
  __syncthreads();
  if (tid == 0) {
    float t = 0.f;
#pragma unroll
    for (int w = 0; w < 8; ++w) t += swred[w];
    const float wgt = (I == J) ? 1.0f : 2.0f;  // off-diag counts twice
    atomicAdd(out, t * wgt * invNN);
  }
}

extern "C" void kernel_launch(void* const* d_in, const int* in_sizes, int n_in,
                              void* d_out, int out_size, void* d_ws, size_t ws_size,
                              hipStream_t stream) {
  const float* emb = (const float*)d_in[0];
  const int* labels = (const int*)d_in[1];
  float* out = (float*)d_out;

  const int N = in_sizes[1];             // 8192
  const int D = in_sizes[0] / N;         // 512
  const int NT = N / 256;                // 32
  const int nTiles = NT * (NT + 1) / 2;  // 528

  u16* e = (u16*)d_ws;

  hipMemsetAsync(out, 0, sizeof(float), stream);
  norm_bf16_k<<<N / 4, 256, 0, stream>>>(emb, e, N, D);
  gram_loss_k<<<nTiles, 512, 0, stream>>>(e, labels, out, N, D, NT, nTiles,
                                          (float)(1.0 / ((double)N * (double)N)));
}